// Round 3
// baseline (381.044 us; speedup 1.0000x reference)
//
#include <hip/hip_runtime.h>

// Problem constants
#define NT 524288          // tokens
#define NE 64              // experts
#define NK 8               // top-k
#define TPB 256            // tokens per block (one thread per token)
#define NBLK (NT / TPB)    // 2048 blocks
#define SPB (TPB * NK)     // 2048 slots per block
#define NTILE (SPB / 256)  // 8 ranking tiles per block

// ---------------------------------------------------------------------------
// Kernel 1: one THREAD per token. 64 logits live in registers; softmax sum is
// computed in the same binary-tree shape as the previous 8-lane version so the
// fp32 result (and thus top-8 selection) is bit-identical. No cross-lane
// shuffles in phase A at all. Phase B: per-block stable arrival-order ranks
// via 6-bit radix ballot match (packed rank*64+e into the offs region).
// ---------------------------------------------------------------------------
__global__ __launch_bounds__(256) void topk_kernel(
    const float* __restrict__ logits,
    float* __restrict__ out_scores,
    float* __restrict__ out_assign,
    float* __restrict__ out_packed,     // offs region, temp: rank*64+e
    float* __restrict__ out_logits,
    int* __restrict__ blockCounts)      // ws: [NBLK][64]
{
    __shared__ unsigned long long pack_lds[TPB];   // 8 ids x 6 bits per token
    __shared__ int running[NE];
    __shared__ int wcnt[4][NE];

    const int t = threadIdx.x;
    const int b = blockIdx.x;
    const int token = b * TPB + t;

    // ---- Phase A: load 64 logits, passthrough, softmax, top-8 ----
    const float* lp = logits + (size_t)token * NE;
    float* op = out_logits + (size_t)token * NE;

    float p[64];
    float m = -__builtin_inff();
    #pragma unroll
    for (int i = 0; i < 16; ++i) {
        float4 v = ((const float4*)lp)[i];
        ((float4*)op)[i] = v;
        p[4*i+0] = v.x; p[4*i+1] = v.y; p[4*i+2] = v.z; p[4*i+3] = v.w;
        m = fmaxf(m, fmaxf(fmaxf(v.x, v.y), fmaxf(v.z, v.w)));
    }

    #pragma unroll
    for (int j = 0; j < 64; ++j) p[j] = expf(p[j] - m);

    // sum in the SAME tree shape as the old 8-lane xor-shuffle reduction:
    // sequential sum of 8 within each group, then xor-pairing g^1, g^2, g^4.
    float s8[8];
    #pragma unroll
    for (int g = 0; g < 8; ++g) {
        float ss = p[g*8];
        #pragma unroll
        for (int j = 1; j < 8; ++j) ss += p[g*8 + j];
        s8[g] = ss;
    }
    float t1[8], t2[8];
    #pragma unroll
    for (int g = 0; g < 8; ++g) t1[g] = s8[g] + s8[g ^ 1];
    #pragma unroll
    for (int g = 0; g < 8; ++g) t2[g] = t1[g] + t1[g ^ 2];
    const float s = t2[0] + t2[4];

    #pragma unroll
    for (int j = 0; j < 64; ++j) p[j] = p[j] / s;   // IEEE div, match ref

    // iterative top-8: strict > over ascending j == max value, smallest index
    float sc[8]; int id[8];
    #pragma unroll
    for (int k = 0; k < NK; ++k) {
        float bv = p[0]; int bi = 0;
        #pragma unroll
        for (int j = 1; j < 64; ++j)
            if (p[j] > bv) { bv = p[j]; bi = j; }
        sc[k] = bv; id[k] = bi;
        #pragma unroll
        for (int j = 0; j < 64; ++j)             // static-index kill
            p[j] = (bi == j) ? -1.0f : p[j];
    }

    // coalesced 32B/thread stores
    float* sp = out_scores + (size_t)token * NK;
    ((float4*)sp)[0] = make_float4(sc[0], sc[1], sc[2], sc[3]);
    ((float4*)sp)[1] = make_float4(sc[4], sc[5], sc[6], sc[7]);
    float* ap = out_assign + (size_t)token * NK;
    ((float4*)ap)[0] = make_float4((float)id[0], (float)id[1], (float)id[2], (float)id[3]);
    ((float4*)ap)[1] = make_float4((float)id[4], (float)id[5], (float)id[6], (float)id[7]);

    unsigned long long pk = 0;
    #pragma unroll
    for (int k = 0; k < NK; ++k) pk |= (unsigned long long)id[k] << (6 * k);
    pack_lds[t] = pk;

    // ---- Phase B: stable in-block ranks over 2048 slots ----
    if (t < NE) running[t] = 0;
    __syncthreads();

    const int w = t >> 6;                // wave 0..3
    const int l = t & 63;                // lane
    const unsigned long long lt_mask = (l == 0) ? 0ull : ((~0ull) >> (64 - l));

    for (int tile = 0; tile < NTILE; ++tile) {
        const int slot_l = tile * 256 + t;              // local slot, in order
        const int e = (int)((pack_lds[slot_l >> 3] >> ((slot_l & 7) * 6)) & 63);

        // 6-bit radix ballot match: mask of lanes with same expert
        unsigned long long mask = ~0ull;
        #pragma unroll
        for (int bit = 0; bit < 6; ++bit) {
            unsigned long long bb = __ballot((e >> bit) & 1);
            mask &= ((e >> bit) & 1) ? bb : ~bb;
        }
        const int r_in_wave = __popcll(mask & lt_mask);
        const int wc = __popcll(mask);

        wcnt[w][l] = 0;                  // covers all 4x64 entries
        __syncthreads();
        if ((mask & lt_mask) == 0ull) wcnt[w][e] = wc;   // group leader
        __syncthreads();

        int before = running[e];
        for (int w2 = 0; w2 < w; ++w2) before += wcnt[w2][e];
        const int rank = before + r_in_wave;

        out_packed[(size_t)b * SPB + slot_l] = (float)(rank * 64 + e);

        __syncthreads();
        if (t < NE) running[t] += wcnt[0][t] + wcnt[1][t] + wcnt[2][t] + wcnt[3][t];
        __syncthreads();
    }

    if (t < NE) blockCounts[b * NE + t] = running[t];
}

// ---------------------------------------------------------------------------
// Kernel 2: per-expert exclusive prefix sum over the 2048 block histograms
// (in place -> block starts). One block per expert. Totals -> counts output.
// ---------------------------------------------------------------------------
__global__ __launch_bounds__(256) void scan_kernel(
    int* __restrict__ blockCounts, float* __restrict__ out_counts)
{
    __shared__ int sdata[256];
    const int e = blockIdx.x;            // 0..63
    const int t = threadIdx.x;           // 0..255
    const int PER = NBLK / 256;          // 8

    int s = 0;
    for (int i = 0; i < PER; ++i) s += blockCounts[(t * PER + i) * NE + e];
    sdata[t] = s;
    __syncthreads();

    // Hillis-Steele inclusive scan over 256 partials
    for (int off = 1; off < 256; off <<= 1) {
        int v = (t >= off) ? sdata[t - off] : 0;
        __syncthreads();
        sdata[t] += v;
        __syncthreads();
    }
    int run = (t == 0) ? 0 : sdata[t - 1];

    for (int i = 0; i < PER; ++i) {
        const int idx = (t * PER + i) * NE + e;
        const int c = blockCounts[idx];
        blockCounts[idx] = run;          // exclusive start for this block
        run += c;
    }
    if (t == 255) out_counts[e] = (float)sdata[255];
}

// ---------------------------------------------------------------------------
// Kernel 3: finalize offsets = blockStart[b][e] + in-block rank (in place).
// ---------------------------------------------------------------------------
__global__ __launch_bounds__(256) void offs_kernel(
    const int* __restrict__ blockCounts, float* __restrict__ out_packed)
{
    __shared__ int base[NE];
    const int b = blockIdx.x;
    const int t = threadIdx.x;
    if (t < NE) base[t] = blockCounts[b * NE + t];
    __syncthreads();
    #pragma unroll
    for (int tile = 0; tile < NTILE; ++tile) {
        const size_t gslot = (size_t)b * SPB + tile * 256 + t;
        const int packed = (int)out_packed[gslot];
        out_packed[gslot] = (float)(base[packed & 63] + (packed >> 6));
    }
}

extern "C" void kernel_launch(void* const* d_in, const int* in_sizes, int n_in,
                              void* d_out, int out_size, void* d_ws, size_t ws_size,
                              hipStream_t stream) {
    // inputs: [0] expert_counts placeholder, [1] assignments placeholder,
    //         [2] offsets placeholder, [3] logits [NT, NE] float32
    const float* logits = (const float*)d_in[3];

    float* out = (float*)d_out;
    float* out_counts = out;                                   // [64]
    float* out_scores = out + NE;                              // [NT*NK]
    float* out_assign = out_scores + (size_t)NT * NK;          // [NT*NK]
    float* out_offs   = out_assign + (size_t)NT * NK;          // [NT*NK]
    float* out_logits = out_offs + (size_t)NT * NK;            // [NT*NE]

    int* blockCounts = (int*)d_ws;                             // 2048*64*4 = 512 KB

    hipLaunchKernelGGL(topk_kernel, dim3(NBLK), dim3(256), 0, stream,
                       logits, out_scores, out_assign, out_offs, out_logits,
                       blockCounts);
    hipLaunchKernelGGL(scan_kernel, dim3(NE), dim3(256), 0, stream,
                       blockCounts, out_counts);
    hipLaunchKernelGGL(offs_kernel, dim3(NBLK), dim3(256), 0, stream,
                       blockCounts, out_offs);
}